// Round 1
// baseline (792.178 us; speedup 1.0000x reference)
//
#include <hip/hip_runtime.h>
#include <math.h>

#define WF 33
#define PLANE_C 2112            // 64*33 complex per plane
#define NBINS 135168            // 64 channels * 2112

__device__ __forceinline__ int bitrev6(int i){
    return ((i&1)<<5) | ((i&2)<<3) | ((i&4)<<1) | ((i&8)>>1) | ((i&16)>>3) | ((i&32)>>5);
}

// Batched 64-point radix-2 FFT on 64 batches living in LDS.
// Element (point i, batch r) at address i*SPT + r*SB. 256 threads.
// Starts and ends with __syncthreads().
template<int SPT, int SB>
__device__ void fft64_all(float* __restrict__ re, float* __restrict__ im,
                          const float* __restrict__ twr, const float* __restrict__ twi,
                          bool inv, int tid)
{
    __syncthreads();
    // bit-reversal permutation along the transform axis
    #pragma unroll
    for (int q = 0; q < 16; q++){
        int idx = tid + q*256;          // 0..4095
        int i = idx >> 6, r = idx & 63;
        int j = bitrev6(i);
        if (i < j){
            int a = i*SPT + r*SB, b = j*SPT + r*SB;
            float t0 = re[a]; re[a] = re[b]; re[b] = t0;
            float t1 = im[a]; im[a] = im[b]; im[b] = t1;
        }
    }
    __syncthreads();
    for (int s = 1; s <= 6; s++){
        int half = 1 << (s-1);
        #pragma unroll
        for (int q = 0; q < 8; q++){
            int flat = tid + q*256;     // 0..2047
            int k = flat >> 6;          // butterfly index 0..31
            int r = flat & 63;          // batch index
            int j = k & (half-1);
            int group = k >> (s-1);
            int i0 = (group << s) + j;
            int i1 = i0 + half;
            int twidx = j << (6 - s);
            float wr = twr[twidx];
            float wi = inv ? -twi[twidx] : twi[twidx];
            int a0 = i0*SPT + r*SB, a1 = i1*SPT + r*SB;
            float xr = re[a1], xi = im[a1];
            float vr = xr*wr - xi*wi;
            float vi = xr*wi + xi*wr;
            float ur = re[a0], ui = im[a0];
            re[a0] = ur + vr; im[a0] = ui + vi;
            re[a1] = ur - vr; im[a1] = ui - vi;
        }
        __syncthreads();
    }
}

__device__ __forceinline__ void build_twiddles(float* twr, float* twi, int tid){
    if (tid < 64){
        float ang = -6.28318530717958647692f * (float)tid * (1.0f/64.0f);
        float s, c;
        sincosf(ang, &s, &c);
        twr[tid] = c;
        twi[tid] = s;
    }
}

// ---------------- K_hat: pad kernel (offset 24,24) and 2-D FFT ----------------
__global__ __launch_bounds__(256) void khat_kernel(const float* __restrict__ ker,
                                                   float2* __restrict__ Khat)
{
    __shared__ float re[64*65];
    __shared__ float im[64*65];
    __shared__ float twr[64], twi[64];
    int tid = threadIdx.x;
    int c = blockIdx.x;

    build_twiddles(twr, twi, tid);
    #pragma unroll
    for (int q = 0; q < 16; q++){
        int idx = tid + q*256;
        re[(idx>>6)*65 + (idx&63)] = 0.f;
        im[(idx>>6)*65 + (idx&63)] = 0.f;
    }
    __syncthreads();
    for (int idx = tid; idx < 225; idx += 256){
        int i = idx / 15, j = idx - i*15;
        re[(24+i)*65 + (24+j)] = ker[c*225 + idx];
    }
    fft64_all<1,65>(re, im, twr, twi, false, tid);   // along w
    fft64_all<65,1>(re, im, twr, twi, false, tid);   // along h

    float2* dst = Khat + (size_t)c * PLANE_C;
    for (int idx = tid; idx < PLANE_C; idx += 256){
        int h = idx / WF, wf = idx - h*WF;
        dst[idx] = make_float2(re[h*65 + wf], im[h*65 + wf]);
    }
}

// ---------------- forward: per (b,t,c) plane 2-D FFT ----------------
__global__ __launch_bounds__(256) void fwd_kernel(const float* __restrict__ x,
                                                  float2* __restrict__ A2)
{
    __shared__ float re[64*65];
    __shared__ float im[64*65];
    __shared__ float twr[64], twi[64];
    int tid = threadIdx.x;
    int blk = blockIdx.x;           // ((b*64+t)*64 + c)
    int c  = blk & 63;
    int bt = blk >> 6;

    build_twiddles(twr, twi, tid);
    const float* xp = x + (size_t)bt * 262144 + c;   // + (h*64+w)*64
    #pragma unroll
    for (int q = 0; q < 16; q++){
        int idx = tid + q*256;      // h*64+w
        re[(idx>>6)*65 + (idx&63)] = xp[(size_t)idx * 64];
        im[(idx>>6)*65 + (idx&63)] = 0.f;
    }
    fft64_all<1,65>(re, im, twr, twi, false, tid);   // along w
    fft64_all<65,1>(re, im, twr, twi, false, tid);   // along h

    float2* dst = A2 + (size_t)blk * PLANE_C;
    for (int idx = tid; idx < PLANE_C; idx += 256){
        int h = idx / WF, wf = idx - h*WF;
        dst[idx] = make_float2(re[h*65 + wf], im[h*65 + wf]);
    }
}

// ---------------- scan: X_t = K*X_{t-1} + U_t per bin, in place ----------------
__global__ __launch_bounds__(256) void scan_kernel(const float2* __restrict__ Khat,
                                                   float2* __restrict__ A2)
{
    int g = blockIdx.x * 256 + threadIdx.x;
    if (g >= 2*NBINS) return;
    int b = (g >= NBINS) ? 1 : 0;
    int j = g - b*NBINS;            // c*2112 + h*33 + wf
    float2 K = Khat[j];
    float ar = 0.f, ai = 0.f;
    size_t base = (size_t)b * 64 * NBINS + j;
    #pragma unroll 4
    for (int t = 0; t < 64; t++){
        float2 u = A2[base];
        float nr = fmaf(K.x, ar, fmaf(-K.y, ai, u.x));
        float ni = fmaf(K.x, ai, fmaf( K.y, ar, u.y));
        ar = nr; ai = ni;
        A2[base] = make_float2(ar, ai);
        base += NBINS;
    }
}

// ---------------- inverse: Hermitian fill + inverse 2-D FFT ----------------
__global__ __launch_bounds__(256) void inv_kernel(const float2* __restrict__ A2,
                                                  float* __restrict__ out)
{
    __shared__ float re[64*65];
    __shared__ float im[64*65];
    __shared__ float twr[64], twi[64];
    int tid = threadIdx.x;
    int blk = blockIdx.x;           // ((b*64+t)*64 + c)
    int c  = blk & 63;
    int bt = blk >> 6;

    build_twiddles(twr, twi, tid);
    const float2* src = A2 + (size_t)blk * PLANE_C;
    for (int idx = tid; idx < PLANE_C; idx += 256){
        int h = idx / WF, wf = idx - h*WF;
        float2 v = src[idx];
        re[h*65 + wf] = v.x;
        im[h*65 + wf] = v.y;
    }
    __syncthreads();
    // Hermitian reconstruction: X[h][w] = conj(X[(-h)%64][64-w]) for w=33..63
    for (int idx = tid; idx < 64*31; idx += 256){
        int h = idx / 31, w = 33 + (idx - (idx/31)*31);
        int sh = (64 - h) & 63, sw = 64 - w;     // sw in 1..31
        re[h*65 + w] =  re[sh*65 + sw];
        im[h*65 + w] = -im[sh*65 + sw];
    }
    fft64_all<65,1>(re, im, twr, twi, true, tid);   // inverse along h
    fft64_all<1,65>(re, im, twr, twi, true, tid);   // inverse along w

    float* op = out + (size_t)bt * 262144 + c;
    const float scale = 1.0f / 4096.0f;
    #pragma unroll
    for (int q = 0; q < 16; q++){
        int idx = tid + q*256;      // h*64+w
        op[(size_t)idx * 64] = re[(idx>>6)*65 + (idx&63)] * scale;
    }
}

extern "C" void kernel_launch(void* const* d_in, const int* in_sizes, int n_in,
                              void* d_out, int out_size, void* d_ws, size_t ws_size,
                              hipStream_t stream)
{
    const float* x   = (const float*)d_in[0];   // (2,64,64,64,64)
    const float* ker = (const float*)d_in[1];   // (64,15,15)
    float* out = (float*)d_out;                 // (2,64,64,64,64)

    float2* Khat = (float2*)d_ws;               // NBINS complex
    float2* A2   = Khat + NBINS;                // 8192 * 2112 complex

    khat_kernel<<<64, 256, 0, stream>>>(ker, Khat);
    fwd_kernel<<<8192, 256, 0, stream>>>(x, A2);
    scan_kernel<<<(2*NBINS + 255)/256, 256, 0, stream>>>(Khat, A2);
    inv_kernel<<<8192, 256, 0, stream>>>(A2, out);
}

// Round 2
// 227.135 us; speedup vs baseline: 3.4877x; 3.4877x over previous
//
#include <hip/hip_runtime.h>
#include <math.h>

#define WF 33
#define NBINS 135168            // 33 wf * 64 h * 64 c complex bins per (b,t)

// ---------------------------------------------------------------------------
// 8-point FFT in registers. DIR = -1 forward (e^{-i...}), +1 inverse.
// ---------------------------------------------------------------------------
template<int DIR>
__device__ __forceinline__ void fft8(float* fr, float* fi){
    const float r = 0.70710678118654752440f;
    float u0r=fr[0]+fr[4], u0i=fi[0]+fi[4];
    float v0r=fr[0]-fr[4], v0i=fi[0]-fi[4];
    float u1r=fr[1]+fr[5], u1i=fi[1]+fi[5];
    float v1r=fr[1]-fr[5], v1i=fi[1]-fi[5];
    float u2r=fr[2]+fr[6], u2i=fi[2]+fi[6];
    float v2r=fr[2]-fr[6], v2i=fi[2]-fi[6];
    float u3r=fr[3]+fr[7], u3i=fi[3]+fi[7];
    float v3r=fr[3]-fr[7], v3i=fi[3]-fi[7];
    float t;
    if (DIR < 0){
        // v1 *= (r,-r); v2 *= -i; v3 *= (-r,-r)
        t = r*(v1r + v1i); v1i = r*(v1i - v1r); v1r = t;
        t = v2i;           v2i = -v2r;          v2r = t;
        t = r*(v3i - v3r); v3i = -r*(v3r + v3i); v3r = t;
    } else {
        // v1 *= (r,r); v2 *= +i; v3 *= (-r,r)
        t = r*(v1r - v1i); v1i = r*(v1i + v1r); v1r = t;
        t = -v2i;          v2i = v2r;           v2r = t;
        t = -r*(v3r + v3i); v3i = r*(v3r - v3i); v3r = t;
    }
    // even half -> X0,X2,X4,X6
    float p0r=u0r+u2r, p0i=u0i+u2i, p1r=u1r+u3r, p1i=u1i+u3i;
    float q0r=u0r-u2r, q0i=u0i-u2i, q1r=u1r-u3r, q1i=u1i-u3i;
    if (DIR < 0){ t=q1i; q1i=-q1r; q1r=t; } else { t=-q1i; q1i=q1r; q1r=t; }
    fr[0]=p0r+p1r; fi[0]=p0i+p1i;
    fr[4]=p0r-p1r; fi[4]=p0i-p1i;
    fr[2]=q0r+q1r; fi[2]=q0i+q1i;
    fr[6]=q0r-q1r; fi[6]=q0i-q1i;
    // odd half -> X1,X3,X5,X7
    p0r=v0r+v2r; p0i=v0i+v2i; p1r=v1r+v3r; p1i=v1i+v3i;
    q0r=v0r-v2r; q0i=v0i-v2i; q1r=v1r-v3r; q1i=v1i-v3i;
    if (DIR < 0){ t=q1i; q1i=-q1r; q1r=t; } else { t=-q1i; q1i=q1r; q1r=t; }
    fr[1]=p0r+p1r; fi[1]=p0i+p1i;
    fr[5]=p0r-p1r; fi[5]=p0i-p1i;
    fr[3]=q0r+q1r; fi[3]=q0i+q1i;
    fr[7]=q0r-q1r; fi[7]=q0i-q1i;
}

// W64 twiddle table: tw[m] = e^{-2*pi*i*m/64} (forward convention)
__device__ __forceinline__ void build_tw64(float* twr, float* twi, int tid){
    if (tid < 64){
        float ang = -6.28318530717958647692f * (float)tid * (1.0f/64.0f);
        float s, c;
        sincosf(ang, &s, &c);
        twr[tid] = c; twi[tid] = s;
    }
}

// Apply W64^{DIR * n2 * k1} to fr/fi[k1], k1 = 1..7 (k1=0 is identity)
template<int DIR>
__device__ __forceinline__ void tw64_apply(float* fr, float* fi, int n2,
                                           const float* twr, const float* twi){
    #pragma unroll
    for (int k1 = 1; k1 < 8; k1++){
        int m = n2 * k1;             // <= 49
        float wr = twr[m];
        float wi = (DIR < 0) ? twi[m] : -twi[m];
        float xr = fr[k1], xi = fi[k1];
        fr[k1] = xr*wr - xi*wi;
        fi[k1] = xr*wi + xi*wr;
    }
}

// ---------------------------------------------------------------------------
// K1: forward FFT along w. block = (bt, h). Reads contiguous 16KB row-slab
// x[bt,h,:,:] (w major, c minor), writes A2[bt][wf][h][c], wf=0..32.
// ---------------------------------------------------------------------------
__global__ __launch_bounds__(256) void k1_row_fwd(const float* __restrict__ x,
                                                  float2* __restrict__ A2){
    __shared__ float2 S[64*64];
    __shared__ float twr[64], twi[64];
    int tid = threadIdx.x;
    int c = tid & 63, idx = tid >> 6;
    int blk = blockIdx.x;
    int h = blk & 63, bt = blk >> 6;

    build_tw64(twr, twi, tid);
    __syncthreads();

    const float* xp = x + (((size_t)bt * 64 + h) << 12);   // *4096
    #pragma unroll
    for (int pass = 0; pass < 2; pass++){
        int n2 = idx + 4*pass;
        float fr[8], fi[8];
        #pragma unroll
        for (int n1 = 0; n1 < 8; n1++){
            fr[n1] = xp[(8*n1 + n2)*64 + c];
            fi[n1] = 0.f;
        }
        fft8<-1>(fr, fi);                 // over n1 -> index k1
        tw64_apply<-1>(fr, fi, n2, twr, twi);
        #pragma unroll
        for (int k1 = 0; k1 < 8; k1++)
            S[(8*n2 + k1)*64 + c] = make_float2(fr[k1], fi[k1]);
    }
    __syncthreads();
    #pragma unroll
    for (int pass = 0; pass < 2; pass++){
        int k1 = idx + 4*pass;
        float fr[8], fi[8];
        #pragma unroll
        for (int n2 = 0; n2 < 8; n2++){
            float2 v = S[(8*n2 + k1)*64 + c];
            fr[n2] = v.x; fi[n2] = v.y;
        }
        fft8<-1>(fr, fi);                 // over n2 -> index k2
        #pragma unroll
        for (int k2 = 0; k2 < 8; k2++){
            int wf = k1 + 8*k2;
            if (wf <= 32)
                A2[(((size_t)bt * WF + wf)*64 + h)*64 + c] = make_float2(fr[k2], fi[k2]);
        }
    }
}

// ---------------------------------------------------------------------------
// K2/K4: FFT along h, in place on the contiguous 32KB slab A2[bt][wf][:][:].
// block = (bt, wf). DIR=-1 forward, +1 inverse (unnormalized).
// ---------------------------------------------------------------------------
template<int DIR>
__global__ __launch_bounds__(256) void kcol(float2* __restrict__ A2){
    __shared__ float2 S[64*64];
    __shared__ float twr[64], twi[64];
    int tid = threadIdx.x;
    int c = tid & 63, idx = tid >> 6;
    int blk = blockIdx.x;
    int wf = blk % WF, bt = blk / WF;

    build_tw64(twr, twi, tid);
    __syncthreads();

    float2* base = A2 + (((size_t)bt * WF + wf) << 12);    // *4096
    #pragma unroll
    for (int pass = 0; pass < 2; pass++){
        int n2 = idx + 4*pass;
        float fr[8], fi[8];
        #pragma unroll
        for (int n1 = 0; n1 < 8; n1++){
            float2 v = base[(8*n1 + n2)*64 + c];
            fr[n1] = v.x; fi[n1] = v.y;
        }
        fft8<DIR>(fr, fi);
        tw64_apply<DIR>(fr, fi, n2, twr, twi);
        #pragma unroll
        for (int k1 = 0; k1 < 8; k1++)
            S[(8*n2 + k1)*64 + c] = make_float2(fr[k1], fi[k1]);
    }
    __syncthreads();   // also guarantees all global loads of the block are done
    #pragma unroll
    for (int pass = 0; pass < 2; pass++){
        int k1 = idx + 4*pass;
        float fr[8], fi[8];
        #pragma unroll
        for (int n2 = 0; n2 < 8; n2++){
            float2 v = S[(8*n2 + k1)*64 + c];
            fr[n2] = v.x; fi[n2] = v.y;
        }
        fft8<DIR>(fr, fi);
        #pragma unroll
        for (int k2 = 0; k2 < 8; k2++)
            base[(k1 + 8*k2)*64 + c] = make_float2(fr[k2], fi[k2]);
    }
}

// ---------------------------------------------------------------------------
// K3: scan  X_t = K*X_{t-1} + U_t  per bin, in place. j = (wf*64+h)*64+c.
// ---------------------------------------------------------------------------
__global__ __launch_bounds__(256) void scan_kernel(const float2* __restrict__ Khat,
                                                   float2* __restrict__ A2){
    int g = blockIdx.x * 256 + threadIdx.x;
    if (g >= 2*NBINS) return;
    int b = (g >= NBINS) ? 1 : 0;
    int j = g - b*NBINS;
    float2 K = Khat[j];
    float ar = 0.f, ai = 0.f;
    size_t base = (size_t)b * 64 * NBINS + j;
    #pragma unroll 4
    for (int t = 0; t < 64; t++){
        float2 u = A2[base];
        float nr = fmaf(K.x, ar, fmaf(-K.y, ai, u.x));
        float ni = fmaf(K.x, ai, fmaf( K.y, ar, u.y));
        ar = nr; ai = ni;
        A2[base] = make_float2(ar, ai);
        base += NBINS;
    }
}

// ---------------------------------------------------------------------------
// K5: inverse FFT along w + Hermitian reconstruction + scale. block = (bt,h).
// Reads A2[bt][wf][h][:] chunks (512B each), writes contiguous 16KB real row.
// ---------------------------------------------------------------------------
__global__ __launch_bounds__(256) void k5_row_inv(const float2* __restrict__ A2,
                                                  float* __restrict__ out){
    __shared__ float2 S[64*64];
    __shared__ float twr[64], twi[64];
    int tid = threadIdx.x;
    int c = tid & 63, idx = tid >> 6;
    int blk = blockIdx.x;
    int h = blk & 63, bt = blk >> 6;

    build_tw64(twr, twi, tid);
    __syncthreads();

    const float2* base = A2 + (size_t)bt * NBINS;   // [wf][h][c]
    #pragma unroll
    for (int pass = 0; pass < 2; pass++){
        int n2 = idx + 4*pass;
        float fr[8], fi[8];
        #pragma unroll
        for (int n1 = 0; n1 < 8; n1++){
            int n = 8*n1 + n2;          // w-frequency index 0..63
            float2 v;
            if (n <= 32){
                v = base[((size_t)n*64 + h)*64 + c];
            } else {
                v = base[((size_t)(64 - n)*64 + h)*64 + c];
                v.y = -v.y;             // conj (symmetry holds per spatial row)
            }
            fr[n1] = v.x; fi[n1] = v.y;
        }
        fft8<1>(fr, fi);
        tw64_apply<1>(fr, fi, n2, twr, twi);
        #pragma unroll
        for (int k1 = 0; k1 < 8; k1++)
            S[(8*n2 + k1)*64 + c] = make_float2(fr[k1], fi[k1]);
    }
    __syncthreads();
    float* op = out + (((size_t)bt * 64 + h) << 12);       // *4096
    const float scale = 1.0f / 4096.0f;
    #pragma unroll
    for (int pass = 0; pass < 2; pass++){
        int k1 = idx + 4*pass;
        float fr[8], fi[8];
        #pragma unroll
        for (int n2 = 0; n2 < 8; n2++){
            float2 v = S[(8*n2 + k1)*64 + c];
            fr[n2] = v.x; fi[n2] = v.y;
        }
        fft8<1>(fr, fi);
        #pragma unroll
        for (int k2 = 0; k2 < 8; k2++)
            op[(k1 + 8*k2)*64 + c] = fr[k2] * scale;
    }
}

// ---------------------------------------------------------------------------
// K0: K_hat via the (small) radix-2 LDS FFT — 64 blocks, negligible cost.
// Writes layout Khat[(wf*64 + h)*64 + c].
// ---------------------------------------------------------------------------
__device__ __forceinline__ int bitrev6(int i){
    return ((i&1)<<5) | ((i&2)<<3) | ((i&4)<<1) | ((i&8)>>1) | ((i&16)>>3) | ((i&32)>>5);
}

template<int SPT, int SB>
__device__ void fft64_all(float* __restrict__ re, float* __restrict__ im,
                          const float* __restrict__ twr, const float* __restrict__ twi,
                          int tid){
    __syncthreads();
    #pragma unroll
    for (int q = 0; q < 16; q++){
        int idx = tid + q*256;
        int i = idx >> 6, r = idx & 63;
        int j = bitrev6(i);
        if (i < j){
            int a = i*SPT + r*SB, b = j*SPT + r*SB;
            float t0 = re[a]; re[a] = re[b]; re[b] = t0;
            float t1 = im[a]; im[a] = im[b]; im[b] = t1;
        }
    }
    __syncthreads();
    for (int s = 1; s <= 6; s++){
        int half = 1 << (s-1);
        #pragma unroll
        for (int q = 0; q < 8; q++){
            int flat = tid + q*256;
            int k = flat >> 6;
            int r = flat & 63;
            int j = k & (half-1);
            int group = k >> (s-1);
            int i0 = (group << s) + j;
            int i1 = i0 + half;
            int twidx = j << (6 - s);
            float wr = twr[twidx], wi = twi[twidx];
            int a0 = i0*SPT + r*SB, a1 = i1*SPT + r*SB;
            float xr = re[a1], xi = im[a1];
            float vr = xr*wr - xi*wi;
            float vi = xr*wi + xi*wr;
            float ur = re[a0], ui = im[a0];
            re[a0] = ur + vr; im[a0] = ui + vi;
            re[a1] = ur - vr; im[a1] = ui - vi;
        }
        __syncthreads();
    }
}

__global__ __launch_bounds__(256) void khat_kernel(const float* __restrict__ ker,
                                                   float2* __restrict__ Khat){
    __shared__ float re[64*65];
    __shared__ float im[64*65];
    __shared__ float twr[64], twi[64];
    int tid = threadIdx.x;
    int c = blockIdx.x;

    build_tw64(twr, twi, tid);
    #pragma unroll
    for (int q = 0; q < 16; q++){
        int idx = tid + q*256;
        re[(idx>>6)*65 + (idx&63)] = 0.f;
        im[(idx>>6)*65 + (idx&63)] = 0.f;
    }
    __syncthreads();
    for (int idx = tid; idx < 225; idx += 256){
        int i = idx / 15, j = idx - i*15;
        re[(24+i)*65 + (24+j)] = ker[c*225 + idx];
    }
    fft64_all<1,65>(re, im, twr, twi, tid);   // along w
    fft64_all<65,1>(re, im, twr, twi, tid);   // along h

    for (int idx = tid; idx < 64*WF; idx += 256){
        int hh = idx / WF, wf = idx - hh*WF;
        Khat[((size_t)wf*64 + hh)*64 + c] = make_float2(re[hh*65 + wf], im[hh*65 + wf]);
    }
}

// ---------------------------------------------------------------------------
extern "C" void kernel_launch(void* const* d_in, const int* in_sizes, int n_in,
                              void* d_out, int out_size, void* d_ws, size_t ws_size,
                              hipStream_t stream)
{
    const float* x   = (const float*)d_in[0];   // (2,64,64,64,64)
    const float* ker = (const float*)d_in[1];   // (64,15,15)
    float* out = (float*)d_out;                 // (2,64,64,64,64)

    float2* Khat = (float2*)d_ws;               // NBINS complex
    float2* A2   = Khat + NBINS;                // 128 * NBINS complex

    khat_kernel<<<64, 256, 0, stream>>>(ker, Khat);
    k1_row_fwd<<<128*64, 256, 0, stream>>>(x, A2);
    kcol<-1><<<128*WF, 256, 0, stream>>>(A2);
    scan_kernel<<<(2*NBINS + 255)/256, 256, 0, stream>>>(Khat, A2);
    kcol<1><<<128*WF, 256, 0, stream>>>(A2);
    k5_row_inv<<<128*64, 256, 0, stream>>>(A2, out);
}

// Round 3
// 209.727 us; speedup vs baseline: 3.7772x; 1.0830x over previous
//
#include <hip/hip_runtime.h>
#include <math.h>

#define WF 33
#define NBINS 135168            // 33 wf * 64 h * 64 c complex bins per (b,t)

// ---------------------------------------------------------------------------
// 8-point FFT in registers. DIR = -1 forward (e^{-i...}), +1 inverse.
// ---------------------------------------------------------------------------
template<int DIR>
__device__ __forceinline__ void fft8(float* fr, float* fi){
    const float r = 0.70710678118654752440f;
    float u0r=fr[0]+fr[4], u0i=fi[0]+fi[4];
    float v0r=fr[0]-fr[4], v0i=fi[0]-fi[4];
    float u1r=fr[1]+fr[5], u1i=fi[1]+fi[5];
    float v1r=fr[1]-fr[5], v1i=fi[1]-fi[5];
    float u2r=fr[2]+fr[6], u2i=fi[2]+fi[6];
    float v2r=fr[2]-fr[6], v2i=fi[2]-fi[6];
    float u3r=fr[3]+fr[7], u3i=fi[3]+fi[7];
    float v3r=fr[3]-fr[7], v3i=fi[3]-fi[7];
    float t;
    if (DIR < 0){
        t = r*(v1r + v1i); v1i = r*(v1i - v1r); v1r = t;
        t = v2i;           v2i = -v2r;          v2r = t;
        t = r*(v3i - v3r); v3i = -r*(v3r + v3i); v3r = t;
    } else {
        t = r*(v1r - v1i); v1i = r*(v1i + v1r); v1r = t;
        t = -v2i;          v2i = v2r;           v2r = t;
        t = -r*(v3r + v3i); v3i = r*(v3r - v3i); v3r = t;
    }
    float p0r=u0r+u2r, p0i=u0i+u2i, p1r=u1r+u3r, p1i=u1i+u3i;
    float q0r=u0r-u2r, q0i=u0i-u2i, q1r=u1r-u3r, q1i=u1i-u3i;
    if (DIR < 0){ t=q1i; q1i=-q1r; q1r=t; } else { t=-q1i; q1i=q1r; q1r=t; }
    fr[0]=p0r+p1r; fi[0]=p0i+p1i;
    fr[4]=p0r-p1r; fi[4]=p0i-p1i;
    fr[2]=q0r+q1r; fi[2]=q0i+q1i;
    fr[6]=q0r-q1r; fi[6]=q0i-q1i;
    p0r=v0r+v2r; p0i=v0i+v2i; p1r=v1r+v3r; p1i=v1i+v3i;
    q0r=v0r-v2r; q0i=v0i-v2i; q1r=v1r-v3r; q1i=v1i-v3i;
    if (DIR < 0){ t=q1i; q1i=-q1r; q1r=t; } else { t=-q1i; q1i=q1r; q1r=t; }
    fr[1]=p0r+p1r; fi[1]=p0i+p1i;
    fr[5]=p0r-p1r; fi[5]=p0i-p1i;
    fr[3]=q0r+q1r; fi[3]=q0i+q1i;
    fr[7]=q0r-q1r; fi[7]=q0i-q1i;
}

__device__ __forceinline__ void build_tw64(float* twr, float* twi, int tid){
    if (tid < 64){
        float ang = -6.28318530717958647692f * (float)tid * (1.0f/64.0f);
        float s, c;
        sincosf(ang, &s, &c);
        twr[tid] = c; twi[tid] = s;
    }
}

// multiply element j (j=1..7) by W64^{DIR * d * j}
template<int DIR>
__device__ __forceinline__ void tw64_apply(float* fr, float* fi, int d,
                                           const float* twr, const float* twi){
    #pragma unroll
    for (int j = 1; j < 8; j++){
        int m = d * j;               // <= 49
        float wr = twr[m];
        float wi = (DIR < 0) ? twi[m] : -twi[m];
        float xr = fr[j], xi = fi[j];
        fr[j] = xr*wr - xi*wi;
        fi[j] = xr*wi + xi*wr;
    }
}

// ---------------------------------------------------------------------------
// K1: forward FFT along w. block = (bt, h). Staged float4 read of the 16KB
// row-slab x[bt,h,:,:]; writes A2[bt][wf][h][c], wf=0..32.
// ---------------------------------------------------------------------------
__global__ __launch_bounds__(256) void k1_row_fwd(const float* __restrict__ x,
                                                  float2* __restrict__ A2){
    __shared__ float2 S[64*64];
    __shared__ float twr[64], twi[64];
    int tid = threadIdx.x;
    int c = tid & 63, idx = tid >> 6;
    int blk = blockIdx.x;
    int h = blk & 63, bt = blk >> 6;

    build_tw64(twr, twi, tid);

    // stage the whole row-slab via float4
    const float4* xp4 = (const float4*)(x + (((size_t)bt * 64 + h) << 12));
    float* Sf = (float*)S;
    #pragma unroll
    for (int q = 0; q < 4; q++)
        ((float4*)Sf)[tid + q*256] = xp4[tid + q*256];
    __syncthreads();

    float in0[8], in1[8];
    #pragma unroll
    for (int n1 = 0; n1 < 8; n1++){
        in0[n1] = Sf[(8*n1 + idx    )*64 + c];
        in1[n1] = Sf[(8*n1 + idx + 4)*64 + c];
    }
    __syncthreads();

    #pragma unroll
    for (int pass = 0; pass < 2; pass++){
        int n2 = idx + 4*pass;
        float fr[8], fi[8];
        #pragma unroll
        for (int n1 = 0; n1 < 8; n1++){
            fr[n1] = pass ? in1[n1] : in0[n1];
            fi[n1] = 0.f;
        }
        fft8<-1>(fr, fi);                 // over n1 -> k1
        tw64_apply<-1>(fr, fi, n2, twr, twi);
        #pragma unroll
        for (int k1 = 0; k1 < 8; k1++)
            S[(8*n2 + k1)*64 + c] = make_float2(fr[k1], fi[k1]);
    }
    __syncthreads();
    #pragma unroll
    for (int pass = 0; pass < 2; pass++){
        int k1 = idx + 4*pass;
        float fr[8], fi[8];
        #pragma unroll
        for (int n2 = 0; n2 < 8; n2++){
            float2 v = S[(8*n2 + k1)*64 + c];
            fr[n2] = v.x; fi[n2] = v.y;
        }
        fft8<-1>(fr, fi);                 // over n2 -> k2
        #pragma unroll
        for (int k2 = 0; k2 < 8; k2++){
            int wf = k1 + 8*k2;
            if (wf <= 32)
                A2[(((size_t)bt * WF + wf)*64 + h)*64 + c] = make_float2(fr[k2], fi[k2]);
        }
    }
}

// ---------------------------------------------------------------------------
// KMID: fused h-FFT + t-scan + inverse h-FFT, in place on A2.
// grid = 2b * 33wf * 8cg single-wave blocks; thread = (c in 8, digit in 8).
// ---------------------------------------------------------------------------
__global__ __launch_bounds__(64) void kmid(const float2* __restrict__ Khat,
                                           float2* __restrict__ A2){
    __shared__ float Sre[64*9 + 8];
    __shared__ float Sim[64*9 + 8];
    __shared__ float twr[64], twi[64];
    int tid = threadIdx.x;
    int c = tid & 7, k = tid >> 3;       // k: n2 in fwd-s1, k1 in fwd-s2/inv
    int u = blockIdx.x;
    int cg  = u & 7;
    int wfb = u >> 3;                    // 0..65
    int wf  = wfb % 33;
    int b   = wfb / 33;
    int cbase = cg*8 + c;

    build_tw64(twr, twi, tid);

    // K fragments: thread (c,k1=k) holds K[fh=k+8k2][cbase]
    float Kr[8], Ki[8];
    const float2* Kp = Khat + (size_t)wf*4096 + cbase;
    #pragma unroll
    for (int k2 = 0; k2 < 8; k2++){
        float2 kv = Kp[(size_t)(k + 8*k2)*64];
        Kr[k2] = kv.x; Ki[k2] = kv.y;
    }
    float Xr[8] = {0,0,0,0,0,0,0,0}, Xi[8] = {0,0,0,0,0,0,0,0};

    size_t slab0 = ((size_t)(b*64) * WF + wf) << 12;   // complex elements
    const size_t tstride = (size_t)WF << 12;

    float ur[8], ui[8], nr[8], ni[8];
    {   // preload t=0
        const float2* p = A2 + slab0 + cbase;
        #pragma unroll
        for (int n1 = 0; n1 < 8; n1++){
            float2 v = p[(size_t)(8*n1 + k)*64];
            ur[n1] = v.x; ui[n1] = v.y;
        }
    }
    __syncthreads();   // twiddles ready

    for (int t = 0; t < 64; t++){
        float2* slab = A2 + slab0 + (size_t)t * tstride;
        if (t < 63){   // prefetch t+1
            const float2* p = slab + tstride + cbase;
            #pragma unroll
            for (int n1 = 0; n1 < 8; n1++){
                float2 v = p[(size_t)(8*n1 + k)*64];
                nr[n1] = v.x; ni[n1] = v.y;
            }
        }
        // ---- forward h-FFT ----
        float fr[8], fi[8];
        #pragma unroll
        for (int i = 0; i < 8; i++){ fr[i]=ur[i]; fi[i]=ui[i]; }
        fft8<-1>(fr, fi);                    // over n1 -> k1
        tw64_apply<-1>(fr, fi, k, twr, twi); // d = n2
        #pragma unroll
        for (int k1 = 0; k1 < 8; k1++){
            int row = 8*k + k1;
            Sre[row*9 + c] = fr[k1];
            Sim[row*9 + c] = fi[k1];
        }
        __syncthreads();
        #pragma unroll
        for (int n2 = 0; n2 < 8; n2++){
            int row = 8*n2 + k;
            fr[n2] = Sre[row*9 + c];
            fi[n2] = Sim[row*9 + c];
        }
        __syncthreads();
        fft8<-1>(fr, fi);                    // over n2 -> k2 : F[k+8k2]
        // ---- scan: X = K*X + U ----
        #pragma unroll
        for (int k2 = 0; k2 < 8; k2++){
            float xr = Xr[k2], xi = Xi[k2];
            Xr[k2] = fmaf(Kr[k2], xr, fmaf(-Ki[k2], xi, fr[k2]));
            Xi[k2] = fmaf(Kr[k2], xi, fmaf( Ki[k2], xr, fi[k2]));
        }
        // ---- inverse h-FFT (unnormalized) ----
        #pragma unroll
        for (int i = 0; i < 8; i++){ fr[i]=Xr[i]; fi[i]=Xi[i]; }
        fft8<1>(fr, fi);                     // over k2 -> h1 (thread-local)
        tw64_apply<1>(fr, fi, k, twr, twi);  // element h1 *= W^{+k1*h1}
        #pragma unroll
        for (int h1 = 0; h1 < 8; h1++){
            int row = 8*h1 + k;
            Sre[row*9 + c] = fr[h1];
            Sim[row*9 + c] = fi[h1];
        }
        __syncthreads();
        #pragma unroll
        for (int k1 = 0; k1 < 8; k1++){
            int row = 8*k + k1;              // k = h1 now
            fr[k1] = Sre[row*9 + c];
            fi[k1] = Sim[row*9 + c];
        }
        __syncthreads();
        fft8<1>(fr, fi);                     // over k1 -> h2 : x[h1+8h2]
        // ---- store slice t (in place) ----
        #pragma unroll
        for (int h2 = 0; h2 < 8; h2++)
            slab[(size_t)(k + 8*h2)*64 + cbase] = make_float2(fr[h2], fi[h2]);
        // rotate prefetch
        #pragma unroll
        for (int i = 0; i < 8; i++){ ur[i]=nr[i]; ui[i]=ni[i]; }
    }
}

// ---------------------------------------------------------------------------
// K5: inverse FFT along w + Hermitian reconstruction + scale. block = (bt,h).
// ---------------------------------------------------------------------------
__global__ __launch_bounds__(256) void k5_row_inv(const float2* __restrict__ A2,
                                                  float* __restrict__ out){
    __shared__ float2 S[64*64];
    __shared__ float twr[64], twi[64];
    int tid = threadIdx.x;
    int c = tid & 63, idx = tid >> 6;
    int blk = blockIdx.x;
    int h = blk & 63, bt = blk >> 6;

    build_tw64(twr, twi, tid);
    __syncthreads();

    const float2* base = A2 + (size_t)bt * NBINS;   // [wf][h][c]
    #pragma unroll
    for (int pass = 0; pass < 2; pass++){
        int n2 = idx + 4*pass;
        float fr[8], fi[8];
        #pragma unroll
        for (int n1 = 0; n1 < 8; n1++){
            int n = 8*n1 + n2;
            float2 v;
            if (n <= 32){
                v = base[((size_t)n*64 + h)*64 + c];
            } else {
                v = base[((size_t)(64 - n)*64 + h)*64 + c];
                v.y = -v.y;
            }
            fr[n1] = v.x; fi[n1] = v.y;
        }
        fft8<1>(fr, fi);
        tw64_apply<1>(fr, fi, n2, twr, twi);
        #pragma unroll
        for (int k1 = 0; k1 < 8; k1++)
            S[(8*n2 + k1)*64 + c] = make_float2(fr[k1], fi[k1]);
    }
    __syncthreads();
    float* op = out + (((size_t)bt * 64 + h) << 12);
    const float scale = 1.0f / 4096.0f;
    #pragma unroll
    for (int pass = 0; pass < 2; pass++){
        int k1 = idx + 4*pass;
        float fr[8], fi[8];
        #pragma unroll
        for (int n2 = 0; n2 < 8; n2++){
            float2 v = S[(8*n2 + k1)*64 + c];
            fr[n2] = v.x; fi[n2] = v.y;
        }
        fft8<1>(fr, fi);
        #pragma unroll
        for (int k2 = 0; k2 < 8; k2++)
            op[(k1 + 8*k2)*64 + c] = fr[k2] * scale;
    }
}

// ---------------------------------------------------------------------------
// K0: K_hat (tiny) — radix-2 LDS FFT. Layout Khat[(wf*64 + h)*64 + c].
// ---------------------------------------------------------------------------
__device__ __forceinline__ int bitrev6(int i){
    return ((i&1)<<5) | ((i&2)<<3) | ((i&4)<<1) | ((i&8)>>1) | ((i&16)>>3) | ((i&32)>>5);
}

template<int SPT, int SB>
__device__ void fft64_all(float* __restrict__ re, float* __restrict__ im,
                          const float* __restrict__ twr, const float* __restrict__ twi,
                          int tid){
    __syncthreads();
    #pragma unroll
    for (int q = 0; q < 16; q++){
        int idx = tid + q*256;
        int i = idx >> 6, r = idx & 63;
        int j = bitrev6(i);
        if (i < j){
            int a = i*SPT + r*SB, b = j*SPT + r*SB;
            float t0 = re[a]; re[a] = re[b]; re[b] = t0;
            float t1 = im[a]; im[a] = im[b]; im[b] = t1;
        }
    }
    __syncthreads();
    for (int s = 1; s <= 6; s++){
        int half = 1 << (s-1);
        #pragma unroll
        for (int q = 0; q < 8; q++){
            int flat = tid + q*256;
            int kk = flat >> 6;
            int r = flat & 63;
            int j = kk & (half-1);
            int group = kk >> (s-1);
            int i0 = (group << s) + j;
            int i1 = i0 + half;
            int twidx = j << (6 - s);
            float wr = twr[twidx], wi = twi[twidx];
            int a0 = i0*SPT + r*SB, a1 = i1*SPT + r*SB;
            float xr = re[a1], xi = im[a1];
            float vr = xr*wr - xi*wi;
            float vi = xr*wi + xi*wr;
            float u0r = re[a0], u0i = im[a0];
            re[a0] = u0r + vr; im[a0] = u0i + vi;
            re[a1] = u0r - vr; im[a1] = u0i - vi;
        }
        __syncthreads();
    }
}

__global__ __launch_bounds__(256) void khat_kernel(const float* __restrict__ ker,
                                                   float2* __restrict__ Khat){
    __shared__ float re[64*65];
    __shared__ float im[64*65];
    __shared__ float twr[64], twi[64];
    int tid = threadIdx.x;
    int c = blockIdx.x;

    build_tw64(twr, twi, tid);
    #pragma unroll
    for (int q = 0; q < 16; q++){
        int idx = tid + q*256;
        re[(idx>>6)*65 + (idx&63)] = 0.f;
        im[(idx>>6)*65 + (idx&63)] = 0.f;
    }
    __syncthreads();
    for (int idx = tid; idx < 225; idx += 256){
        int i = idx / 15, j = idx - i*15;
        re[(24+i)*65 + (24+j)] = ker[c*225 + idx];
    }
    fft64_all<1,65>(re, im, twr, twi, tid);   // along w
    fft64_all<65,1>(re, im, twr, twi, tid);   // along h

    for (int idx = tid; idx < 64*WF; idx += 256){
        int hh = idx / WF, wf = idx - hh*WF;
        Khat[((size_t)wf*64 + hh)*64 + c] = make_float2(re[hh*65 + wf], im[hh*65 + wf]);
    }
}

// ---------------------------------------------------------------------------
extern "C" void kernel_launch(void* const* d_in, const int* in_sizes, int n_in,
                              void* d_out, int out_size, void* d_ws, size_t ws_size,
                              hipStream_t stream)
{
    const float* x   = (const float*)d_in[0];   // (2,64,64,64,64)
    const float* ker = (const float*)d_in[1];   // (64,15,15)
    float* out = (float*)d_out;                 // (2,64,64,64,64)

    float2* Khat = (float2*)d_ws;               // NBINS complex
    float2* A2   = Khat + NBINS;                // 128 * NBINS complex

    khat_kernel<<<64, 256, 0, stream>>>(ker, Khat);
    k1_row_fwd<<<128*64, 256, 0, stream>>>(x, A2);
    kmid<<<2*33*8, 64, 0, stream>>>(Khat, A2);
    k5_row_inv<<<128*64, 256, 0, stream>>>(A2, out);
}

// Round 4
// 166.354 us; speedup vs baseline: 4.7620x; 1.2607x over previous
//
#include <hip/hip_runtime.h>
#include <hip/hip_fp16.h>
#include <math.h>

#define WF 33
#define TSLAB 135168            // 33 wf * 64 h * 64 c complex per (b,t)
#define PBINS 270336            // 2 b * 33 wf * 64 fh * 64 c

struct __align__(8) H4 { __half2 a, b; };

// ---------------------------------------------------------------------------
// 8-point FFT in registers. DIR = -1 forward, +1 inverse.
// ---------------------------------------------------------------------------
template<int DIR>
__device__ __forceinline__ void fft8(float* fr, float* fi){
    const float r = 0.70710678118654752440f;
    float u0r=fr[0]+fr[4], u0i=fi[0]+fi[4];
    float v0r=fr[0]-fr[4], v0i=fi[0]-fi[4];
    float u1r=fr[1]+fr[5], u1i=fi[1]+fi[5];
    float v1r=fr[1]-fr[5], v1i=fi[1]-fi[5];
    float u2r=fr[2]+fr[6], u2i=fi[2]+fi[6];
    float v2r=fr[2]-fr[6], v2i=fi[2]-fi[6];
    float u3r=fr[3]+fr[7], u3i=fi[3]+fi[7];
    float v3r=fr[3]-fr[7], v3i=fi[3]-fi[7];
    float t;
    if (DIR < 0){
        t = r*(v1r + v1i); v1i = r*(v1i - v1r); v1r = t;
        t = v2i;           v2i = -v2r;          v2r = t;
        t = r*(v3i - v3r); v3i = -r*(v3r + v3i); v3r = t;
    } else {
        t = r*(v1r - v1i); v1i = r*(v1i + v1r); v1r = t;
        t = -v2i;          v2i = v2r;           v2r = t;
        t = -r*(v3r + v3i); v3i = r*(v3r - v3i); v3r = t;
    }
    float p0r=u0r+u2r, p0i=u0i+u2i, p1r=u1r+u3r, p1i=u1i+u3i;
    float q0r=u0r-u2r, q0i=u0i-u2i, q1r=u1r-u3r, q1i=u1i-u3i;
    if (DIR < 0){ t=q1i; q1i=-q1r; q1r=t; } else { t=-q1i; q1i=q1r; q1r=t; }
    fr[0]=p0r+p1r; fi[0]=p0i+p1i;
    fr[4]=p0r-p1r; fi[4]=p0i-p1i;
    fr[2]=q0r+q1r; fi[2]=q0i+q1i;
    fr[6]=q0r-q1r; fi[6]=q0i-q1i;
    p0r=v0r+v2r; p0i=v0i+v2i; p1r=v1r+v3r; p1i=v1i+v3i;
    q0r=v0r-v2r; q0i=v0i-v2i; q1r=v1r-v3r; q1i=v1i-v3i;
    if (DIR < 0){ t=q1i; q1i=-q1r; q1r=t; } else { t=-q1i; q1i=q1r; q1r=t; }
    fr[1]=p0r+p1r; fi[1]=p0i+p1i;
    fr[5]=p0r-p1r; fi[5]=p0i-p1i;
    fr[3]=q0r+q1r; fi[3]=q0i+q1i;
    fr[7]=q0r-q1r; fi[7]=q0i-q1i;
}

__device__ __forceinline__ void build_tw64(float* twr, float* twi, int tid){
    if (tid < 64){
        float ang = -6.28318530717958647692f * (float)tid * (1.0f/64.0f);
        float s, c;
        sincosf(ang, &s, &c);
        twr[tid] = c; twi[tid] = s;
    }
}

template<int DIR>
__device__ __forceinline__ void tw64_apply(float* fr, float* fi, int d,
                                           const float* twr, const float* twi){
    #pragma unroll
    for (int j = 1; j < 8; j++){
        int m = d * j;
        float wr = twr[m];
        float wi = (DIR < 0) ? twi[m] : -twi[m];
        float xr = fr[j], xi = fi[j];
        fr[j] = xr*wr - xi*wi;
        fi[j] = xr*wi + xi*wr;
    }
}

// ---------------------------------------------------------------------------
// K1: forward FFT along w. block=(bt,h). Reads contiguous 16KB row-slab,
// writes A2[bt][wf][h][c] fp16, wf=0..32.
// ---------------------------------------------------------------------------
__global__ __launch_bounds__(256) void k1_row_fwd(const float* __restrict__ x,
                                                  __half2* __restrict__ A2){
    __shared__ float2 S[64*64];
    __shared__ float twr[64], twi[64];
    int tid = threadIdx.x;
    int c = tid & 63, idx = tid >> 6;
    int blk = blockIdx.x;
    int h = blk & 63, bt = blk >> 6;

    build_tw64(twr, twi, tid);

    const float4* xp4 = (const float4*)(x + (((size_t)bt * 64 + h) << 12));
    float* Sf = (float*)S;
    #pragma unroll
    for (int q = 0; q < 4; q++)
        ((float4*)Sf)[tid + q*256] = xp4[tid + q*256];
    __syncthreads();

    float in0[8], in1[8];
    #pragma unroll
    for (int n1 = 0; n1 < 8; n1++){
        in0[n1] = Sf[(8*n1 + idx    )*64 + c];
        in1[n1] = Sf[(8*n1 + idx + 4)*64 + c];
    }
    __syncthreads();

    #pragma unroll
    for (int pass = 0; pass < 2; pass++){
        int n2 = idx + 4*pass;
        float fr[8], fi[8];
        #pragma unroll
        for (int n1 = 0; n1 < 8; n1++){
            fr[n1] = pass ? in1[n1] : in0[n1];
            fi[n1] = 0.f;
        }
        fft8<-1>(fr, fi);
        tw64_apply<-1>(fr, fi, n2, twr, twi);
        #pragma unroll
        for (int k1 = 0; k1 < 8; k1++)
            S[(8*n2 + k1)*64 + c] = make_float2(fr[k1], fi[k1]);
    }
    __syncthreads();
    #pragma unroll
    for (int pass = 0; pass < 2; pass++){
        int k1 = idx + 4*pass;
        float fr[8], fi[8];
        #pragma unroll
        for (int n2 = 0; n2 < 8; n2++){
            float2 v = S[(8*n2 + k1)*64 + c];
            fr[n2] = v.x; fi[n2] = v.y;
        }
        fft8<-1>(fr, fi);
        #pragma unroll
        for (int k2 = 0; k2 < 8; k2++){
            int wf = k1 + 8*k2;
            if (wf <= 32)
                A2[(((size_t)bt * WF + wf)*64 + h)*64 + c] =
                    __floats2half2_rn(fr[k2], fi[k2]);
        }
    }
}

// ---------------------------------------------------------------------------
// KA: per-chunk forward h-FFT + LOCAL scan (zero init), in place; carry out.
// grid = 2b*33wf*4cg*8chunk = 2112 single-wave blocks.
// lane = (cp in 8, k in 8); each lane owns columns c0=cg*16+2cp and c0+1.
// ---------------------------------------------------------------------------
__global__ __launch_bounds__(64) void kA(const float2* __restrict__ Khat,
                                         __half2* __restrict__ A2,
                                         float2* __restrict__ Lc){
    __shared__ float Sre[64*17], Sim[64*17];
    __shared__ float twr[64], twi[64];
    int tid = threadIdx.x;
    int cp = tid & 7, k = tid >> 3;
    int u = blockIdx.x;
    int chunk = u & 7;
    int cg = (u >> 3) & 3;
    int wfb = u >> 5;                    // 0..65
    int wf = wfb % 33, b = wfb / 33;
    int c0 = cg*16 + 2*cp;

    build_tw64(twr, twi, tid);

    float K0r[8], K0i[8], K1r[8], K1i[8];
    {
        const float2* Kb = Khat + (size_t)wf*4096 + c0;
        #pragma unroll
        for (int k2 = 0; k2 < 8; k2++){
            float4 kv = *(const float4*)(Kb + (size_t)(k + 8*k2)*64);
            K0r[k2]=kv.x; K0i[k2]=kv.y; K1r[k2]=kv.z; K1i[k2]=kv.w;
        }
    }
    float X0r[8]={0},X0i[8]={0},X1r[8]={0},X1i[8]={0};

    size_t sbase = ((size_t)(b*64 + chunk*8)*WF + wf)*4096;
    const size_t TS = TSLAB;

    H4 pre[8];
    {
        const __half2* p = A2 + sbase + c0;
        #pragma unroll
        for (int n1 = 0; n1 < 8; n1++)
            pre[n1] = *(const H4*)(p + (size_t)(8*n1 + k)*64);
    }
    __syncthreads();

    for (int d = 0; d < 8; d++){
        size_t sl = sbase + (size_t)d*TS;
        H4 cur[8];
        #pragma unroll
        for (int i = 0; i < 8; i++) cur[i] = pre[i];
        if (d < 7){
            const __half2* p = A2 + sl + TS + c0;
            #pragma unroll
            for (int n1 = 0; n1 < 8; n1++)
                pre[n1] = *(const H4*)(p + (size_t)(8*n1 + k)*64);
        }
        float f0r[8],f0i[8],f1r[8],f1i[8];
        #pragma unroll
        for (int n1 = 0; n1 < 8; n1++){
            float2 a = __half22float2(cur[n1].a);
            float2 bb = __half22float2(cur[n1].b);
            f0r[n1]=a.x; f0i[n1]=a.y; f1r[n1]=bb.x; f1i[n1]=bb.y;
        }
        fft8<-1>(f0r,f0i); tw64_apply<-1>(f0r,f0i,k,twr,twi);
        fft8<-1>(f1r,f1i); tw64_apply<-1>(f1r,f1i,k,twr,twi);
        __syncthreads();
        #pragma unroll
        for (int k1 = 0; k1 < 8; k1++){
            int row = (8*k + k1)*17 + 2*cp;
            Sre[row]   = f0r[k1]; Sim[row]   = f0i[k1];
            Sre[row+1] = f1r[k1]; Sim[row+1] = f1i[k1];
        }
        __syncthreads();
        #pragma unroll
        for (int n2 = 0; n2 < 8; n2++){
            int row = (8*n2 + k)*17 + 2*cp;
            f0r[n2]=Sre[row];   f0i[n2]=Sim[row];
            f1r[n2]=Sre[row+1]; f1i[n2]=Sim[row+1];
        }
        fft8<-1>(f0r,f0i);
        fft8<-1>(f1r,f1i);
        __half2* sp = A2 + sl + c0;
        #pragma unroll
        for (int k2 = 0; k2 < 8; k2++){
            float xr, xi;
            xr = X0r[k2]; xi = X0i[k2];
            X0r[k2] = fmaf(K0r[k2], xr, fmaf(-K0i[k2], xi, f0r[k2]));
            X0i[k2] = fmaf(K0r[k2], xi, fmaf( K0i[k2], xr, f0i[k2]));
            xr = X1r[k2]; xi = X1i[k2];
            X1r[k2] = fmaf(K1r[k2], xr, fmaf(-K1i[k2], xi, f1r[k2]));
            X1i[k2] = fmaf(K1r[k2], xi, fmaf( K1i[k2], xr, f1i[k2]));
            H4 w;
            w.a = __floats2half2_rn(X0r[k2], X0i[k2]);
            w.b = __floats2half2_rn(X1r[k2], X1i[k2]);
            *(H4*)(sp + (size_t)(k + 8*k2)*64) = w;
        }
    }
    float2* Lb = Lc + (size_t)chunk*PBINS + ((size_t)b*WF + wf)*4096 + c0;
    #pragma unroll
    for (int k2 = 0; k2 < 8; k2++)
        *(float4*)(Lb + (size_t)(k + 8*k2)*64) =
            make_float4(X0r[k2], X0i[k2], X1r[k2], X1i[k2]);
}

// ---------------------------------------------------------------------------
// KB: sequential 8-chunk combine per bin. F_j = L_j + K^8 F_{j-1}; Cin_j=F_{j-1}.
// ---------------------------------------------------------------------------
__global__ __launch_bounds__(256) void kB(const float2* __restrict__ Khat,
                                          const float2* __restrict__ Lc,
                                          float2* __restrict__ Cin){
    int g = blockIdx.x*256 + threadIdx.x;    // exactly PBINS threads
    int c = g & 63;
    int fh = (g >> 6) & 63;
    int rest = g >> 12;                      // b*33 + wf
    int wf = rest % 33;
    float2 K = Khat[((size_t)wf*64 + fh)*64 + c];
    float kr = K.x, ki = K.y;
    #pragma unroll
    for (int i = 0; i < 3; i++){             // K^8
        float nr = kr*kr - ki*ki;
        float ni = 2.f*kr*ki;
        kr = nr; ki = ni;
    }
    float Fr = 0.f, Fi = 0.f;
    #pragma unroll
    for (int j = 0; j < 8; j++){
        Cin[(size_t)j*PBINS + g] = make_float2(Fr, Fi);
        float2 L = Lc[(size_t)j*PBINS + g];
        float nr = fmaf(kr, Fr, fmaf(-ki, Fi, L.x));
        float ni = fmaf(kr, Fi, fmaf( ki, Fr, L.y));
        Fr = nr; Fi = ni;
    }
}

// ---------------------------------------------------------------------------
// KC: correction X = X' + K^{d+1}*Cin, inverse h-FFT, scale 1/64, in place.
// ---------------------------------------------------------------------------
__global__ __launch_bounds__(64) void kC(const float2* __restrict__ Khat,
                                         const float2* __restrict__ Cin,
                                         __half2* __restrict__ A2){
    __shared__ float Sre[64*17], Sim[64*17];
    __shared__ float twr[64], twi[64];
    int tid = threadIdx.x;
    int cp = tid & 7, k = tid >> 3;
    int u = blockIdx.x;
    int chunk = u & 7;
    int cg = (u >> 3) & 3;
    int wfb = u >> 5;
    int wf = wfb % 33, b = wfb / 33;
    int c0 = cg*16 + 2*cp;

    build_tw64(twr, twi, tid);

    float K0r[8], K0i[8], K1r[8], K1i[8];
    {
        const float2* Kb = Khat + (size_t)wf*4096 + c0;
        #pragma unroll
        for (int k2 = 0; k2 < 8; k2++){
            float4 kv = *(const float4*)(Kb + (size_t)(k + 8*k2)*64);
            K0r[k2]=kv.x; K0i[k2]=kv.y; K1r[k2]=kv.z; K1i[k2]=kv.w;
        }
    }
    float P0r[8],P0i[8],P1r[8],P1i[8];
    {
        const float2* Cb = Cin + (size_t)chunk*PBINS + ((size_t)b*WF + wf)*4096 + c0;
        #pragma unroll
        for (int k2 = 0; k2 < 8; k2++){
            float4 s = *(const float4*)(Cb + (size_t)(k + 8*k2)*64);
            P0r[k2] = K0r[k2]*s.x - K0i[k2]*s.y;
            P0i[k2] = K0r[k2]*s.y + K0i[k2]*s.x;
            P1r[k2] = K1r[k2]*s.z - K1i[k2]*s.w;
            P1i[k2] = K1r[k2]*s.w + K1i[k2]*s.z;
        }
    }

    size_t sbase = ((size_t)(b*64 + chunk*8)*WF + wf)*4096;
    const size_t TS = TSLAB;

    H4 pre[8];
    {
        const __half2* p = A2 + sbase + c0;
        #pragma unroll
        for (int k2 = 0; k2 < 8; k2++)
            pre[k2] = *(const H4*)(p + (size_t)(k + 8*k2)*64);
    }
    __syncthreads();

    for (int d = 0; d < 8; d++){
        size_t sl = sbase + (size_t)d*TS;
        H4 cur[8];
        #pragma unroll
        for (int i = 0; i < 8; i++) cur[i] = pre[i];
        if (d < 7){
            const __half2* p = A2 + sl + TS + c0;
            #pragma unroll
            for (int k2 = 0; k2 < 8; k2++)
                pre[k2] = *(const H4*)(p + (size_t)(k + 8*k2)*64);
        }
        float f0r[8],f0i[8],f1r[8],f1i[8];
        #pragma unroll
        for (int k2 = 0; k2 < 8; k2++){
            float2 a = __half22float2(cur[k2].a);
            float2 bb = __half22float2(cur[k2].b);
            f0r[k2] = a.x + P0r[k2];  f0i[k2] = a.y + P0i[k2];
            f1r[k2] = bb.x + P1r[k2]; f1i[k2] = bb.y + P1i[k2];
            float pr, pi;
            pr = P0r[k2]; pi = P0i[k2];
            P0r[k2] = K0r[k2]*pr - K0i[k2]*pi;
            P0i[k2] = K0r[k2]*pi + K0i[k2]*pr;
            pr = P1r[k2]; pi = P1i[k2];
            P1r[k2] = K1r[k2]*pr - K1i[k2]*pi;
            P1i[k2] = K1r[k2]*pi + K1i[k2]*pr;
        }
        fft8<1>(f0r,f0i); tw64_apply<1>(f0r,f0i,k,twr,twi);
        fft8<1>(f1r,f1i); tw64_apply<1>(f1r,f1i,k,twr,twi);
        __syncthreads();
        #pragma unroll
        for (int h1 = 0; h1 < 8; h1++){
            int row = (8*h1 + k)*17 + 2*cp;
            Sre[row]   = f0r[h1]; Sim[row]   = f0i[h1];
            Sre[row+1] = f1r[h1]; Sim[row+1] = f1i[h1];
        }
        __syncthreads();
        #pragma unroll
        for (int k1 = 0; k1 < 8; k1++){
            int row = (8*k + k1)*17 + 2*cp;
            f0r[k1]=Sre[row];   f0i[k1]=Sim[row];
            f1r[k1]=Sre[row+1]; f1i[k1]=Sim[row+1];
        }
        fft8<1>(f0r,f0i);
        fft8<1>(f1r,f1i);
        const float sc = 1.0f/64.0f;
        __half2* sp = A2 + sl + c0;
        #pragma unroll
        for (int h2 = 0; h2 < 8; h2++){
            H4 w;
            w.a = __floats2half2_rn(f0r[h2]*sc, f0i[h2]*sc);
            w.b = __floats2half2_rn(f1r[h2]*sc, f1i[h2]*sc);
            *(H4*)(sp + (size_t)(k + 8*h2)*64) = w;
        }
    }
}

// ---------------------------------------------------------------------------
// K5: inverse FFT along w + Hermitian + final 1/64 scale. block=(bt,h).
// ---------------------------------------------------------------------------
__global__ __launch_bounds__(256) void k5_row_inv(const __half2* __restrict__ A2,
                                                  float* __restrict__ out){
    __shared__ float2 S[64*64];
    __shared__ float twr[64], twi[64];
    int tid = threadIdx.x;
    int c = tid & 63, idx = tid >> 6;
    int blk = blockIdx.x;
    int h = blk & 63, bt = blk >> 6;

    build_tw64(twr, twi, tid);
    __syncthreads();

    const __half2* base = A2 + (size_t)bt * TSLAB;   // [wf][h][c]
    #pragma unroll
    for (int pass = 0; pass < 2; pass++){
        int n2 = idx + 4*pass;
        float fr[8], fi[8];
        #pragma unroll
        for (int n1 = 0; n1 < 8; n1++){
            int n = 8*n1 + n2;
            float2 v;
            if (n <= 32){
                v = __half22float2(base[((size_t)n*64 + h)*64 + c]);
            } else {
                v = __half22float2(base[((size_t)(64 - n)*64 + h)*64 + c]);
                v.y = -v.y;
            }
            fr[n1] = v.x; fi[n1] = v.y;
        }
        fft8<1>(fr, fi);
        tw64_apply<1>(fr, fi, n2, twr, twi);
        #pragma unroll
        for (int k1 = 0; k1 < 8; k1++)
            S[(8*n2 + k1)*64 + c] = make_float2(fr[k1], fi[k1]);
    }
    __syncthreads();
    float* op = out + (((size_t)bt * 64 + h) << 12);
    const float scale = 1.0f / 64.0f;
    #pragma unroll
    for (int pass = 0; pass < 2; pass++){
        int k1 = idx + 4*pass;
        float fr[8], fi[8];
        #pragma unroll
        for (int n2 = 0; n2 < 8; n2++){
            float2 v = S[(8*n2 + k1)*64 + c];
            fr[n2] = v.x; fi[n2] = v.y;
        }
        fft8<1>(fr, fi);
        #pragma unroll
        for (int k2 = 0; k2 < 8; k2++)
            op[(k1 + 8*k2)*64 + c] = fr[k2] * scale;
    }
}

// ---------------------------------------------------------------------------
// K0: K_hat (tiny) — radix-2 LDS FFT. Layout Khat[(wf*64 + fh)*64 + c], fp32.
// ---------------------------------------------------------------------------
__device__ __forceinline__ int bitrev6(int i){
    return ((i&1)<<5) | ((i&2)<<3) | ((i&4)<<1) | ((i&8)>>1) | ((i&16)>>3) | ((i&32)>>5);
}

template<int SPT, int SB>
__device__ void fft64_all(float* __restrict__ re, float* __restrict__ im,
                          const float* __restrict__ twr, const float* __restrict__ twi,
                          int tid){
    __syncthreads();
    #pragma unroll
    for (int q = 0; q < 16; q++){
        int idx = tid + q*256;
        int i = idx >> 6, r = idx & 63;
        int j = bitrev6(i);
        if (i < j){
            int a = i*SPT + r*SB, b = j*SPT + r*SB;
            float t0 = re[a]; re[a] = re[b]; re[b] = t0;
            float t1 = im[a]; im[a] = im[b]; im[b] = t1;
        }
    }
    __syncthreads();
    for (int s = 1; s <= 6; s++){
        int half = 1 << (s-1);
        #pragma unroll
        for (int q = 0; q < 8; q++){
            int flat = tid + q*256;
            int kk = flat >> 6;
            int r = flat & 63;
            int j = kk & (half-1);
            int group = kk >> (s-1);
            int i0 = (group << s) + j;
            int i1 = i0 + half;
            int twidx = j << (6 - s);
            float wr = twr[twidx], wi = twi[twidx];
            int a0 = i0*SPT + r*SB, a1 = i1*SPT + r*SB;
            float xr = re[a1], xi = im[a1];
            float vr = xr*wr - xi*wi;
            float vi = xr*wi + xi*wr;
            float u0r = re[a0], u0i = im[a0];
            re[a0] = u0r + vr; im[a0] = u0i + vi;
            re[a1] = u0r - vr; im[a1] = u0i - vi;
        }
        __syncthreads();
    }
}

__global__ __launch_bounds__(256) void khat_kernel(const float* __restrict__ ker,
                                                   float2* __restrict__ Khat){
    __shared__ float re[64*65];
    __shared__ float im[64*65];
    __shared__ float twr[64], twi[64];
    int tid = threadIdx.x;
    int c = blockIdx.x;

    build_tw64(twr, twi, tid);
    #pragma unroll
    for (int q = 0; q < 16; q++){
        int idx = tid + q*256;
        re[(idx>>6)*65 + (idx&63)] = 0.f;
        im[(idx>>6)*65 + (idx&63)] = 0.f;
    }
    __syncthreads();
    for (int idx = tid; idx < 225; idx += 256){
        int i = idx / 15, j = idx - i*15;
        re[(24+i)*65 + (24+j)] = ker[c*225 + idx];
    }
    fft64_all<1,65>(re, im, twr, twi, tid);
    fft64_all<65,1>(re, im, twr, twi, tid);

    for (int idx = tid; idx < 64*WF; idx += 256){
        int fh = idx / WF, wf = idx - fh*WF;
        Khat[((size_t)wf*64 + fh)*64 + c] = make_float2(re[fh*65 + wf], im[fh*65 + wf]);
    }
}

// ---------------------------------------------------------------------------
extern "C" void kernel_launch(void* const* d_in, const int* in_sizes, int n_in,
                              void* d_out, int out_size, void* d_ws, size_t ws_size,
                              hipStream_t stream)
{
    const float* x   = (const float*)d_in[0];   // (2,64,64,64,64)
    const float* ker = (const float*)d_in[1];   // (64,15,15)
    float* out = (float*)d_out;                 // (2,64,64,64,64)

    char* ws = (char*)d_ws;
    float2*  Khat = (float2*)ws;                            //   1,081,344 B
    __half2* A2   = (__half2*)(ws + 1081344);               //  69,206,016 B
    float2*  Lc   = (float2*)(ws + 1081344 + 69206016);     //  17,301,504 B
    float2*  Cin  = Lc + (size_t)8*PBINS;                   //  17,301,504 B

    khat_kernel<<<64, 256, 0, stream>>>(ker, Khat);
    k1_row_fwd<<<8192, 256, 0, stream>>>(x, A2);
    kA<<<2112, 64, 0, stream>>>(Khat, A2, Lc);
    kB<<<PBINS/256, 256, 0, stream>>>(Khat, Lc, Cin);
    kC<<<2112, 64, 0, stream>>>(Khat, Cin, A2);
    k5_row_inv<<<8192, 256, 0, stream>>>(A2, out);
}